// Round 1
// baseline (985.295 us; speedup 1.0000x reference)
//
#include <hip/hip_runtime.h>
#include <math.h>

#define F_IN 12
#define NHID 64
#define HGCN 61
#define EMB_OUT 54

__device__ __forceinline__ float gelu_exact(float v) {
    return 0.5f * v * (1.0f + erff(v * 0.70710678118654752440f));
}

__device__ __forceinline__ void atomic_add_f32(float* p, float v) {
    // guarantee hardware global_atomic_add_f32 (no CAS loop)
    unsafeAtomicAdd(p, v);
}

// ---- prep: softmax(msg_weights) -> sp[3]; fold W_emb/b_emb into W_gcn -> W_eff(12x64), b_eff(64)
__global__ void prep_kernel(const float* __restrict__ msg_w,
                            const float* __restrict__ W_emb,
                            const float* __restrict__ b_emb,
                            const float* __restrict__ W_gcn,
                            float* __restrict__ sp,
                            float* __restrict__ W_eff,
                            float* __restrict__ b_eff) {
    int t = threadIdx.x;
    if (t == 0) {
        float m = fmaxf(msg_w[0], fmaxf(msg_w[1], msg_w[2]));
        float e0 = expf(msg_w[0] - m), e1 = expf(msg_w[1] - m), e2 = expf(msg_w[2] - m);
        float s = e0 + e1 + e2;
        sp[0] = e0 / s; sp[1] = e1 / s; sp[2] = e2 / s;
    }
    if (t < HGCN) {
        float be = 0.f, w0 = 0.f, w1 = 0.f;
        for (int k = 0; k < EMB_OUT; ++k) {
            float g = W_gcn[k * HGCN + t];        // W_gcn[k][t], (64,61) row-major
            be += b_emb[k] * g;
            w0 += W_emb[k] * g;                   // W_emb[0][k]
            w1 += W_emb[EMB_OUT + k] * g;         // W_emb[1][k]
        }
        b_eff[t] = be;
        W_eff[0 * 64 + t] = w0;
        W_eff[1 * 64 + t] = w1;
        for (int f = 2; f < F_IN; ++f)
            W_eff[f * 64 + t] = W_gcn[(EMB_OUT + f - 2) * HGCN + t];
    }
}

__global__ void init_ew_kernel(float* __restrict__ ew, int E) {
    int i = blockIdx.x * blockDim.x + threadIdx.x;
    if (i < E) ew[i] = 1.0f;
}

__global__ void set_mask_kernel(float* __restrict__ ew, const int* __restrict__ mask,
                                const float* __restrict__ spv, int n) {
    int i = blockIdx.x * blockDim.x + threadIdx.x;
    if (i < n) ew[mask[i]] = *spv;
}

__global__ void deg_init_kernel(float* __restrict__ deg, int n) {
    int i = blockIdx.x * blockDim.x + threadIdx.x;
    if (i < n) deg[i] = 1.0f;   // self-loop weight
}

__global__ void deg_accum_kernel(const int* __restrict__ ei, const float* __restrict__ ew,
                                 float* __restrict__ deg, int E) {
    int e = blockIdx.x * blockDim.x + threadIdx.x;
    if (e < E) atomic_add_f32(&deg[ei[E + e]], ew[e]);  // col = ei[1][e]
}

__global__ void dis_kernel(float* __restrict__ deg, int n) {
    int i = blockIdx.x * blockDim.x + threadIdx.x;
    if (i < n) deg[i] = rsqrtf(deg[i]);   // deg >= 1 always (self-loop)
}

// h2 = x @ W_eff + b_eff (stride-64 padded); outacc initialized with self-loop term dis^2 * h2
__global__ void h2_kernel(const float* __restrict__ x, const float* __restrict__ W_eff,
                          const float* __restrict__ b_eff, const float* __restrict__ dis,
                          float* __restrict__ h2, float* __restrict__ outacc, int n_nodes) {
    int node = blockIdx.x * 4 + (threadIdx.x >> 6);
    int d = threadIdx.x & 63;
    if (node >= n_nodes) return;
    float v = 0.f;
    if (d < HGCN) {
        v = b_eff[d];
#pragma unroll
        for (int f = 0; f < F_IN; ++f)
            v += x[node * F_IN + f] * W_eff[f * 64 + d];
    }
    h2[node * 64 + d] = v;
    float di = dis[node];
    outacc[node * 64 + d] = di * di * v;
}

// one wave per edge: out[col] += dis[row]*ew*dis[col] * h2[row]
__global__ void scatter_kernel(const int* __restrict__ ei, const float* __restrict__ ew,
                               const float* __restrict__ dis, const float* __restrict__ h2,
                               float* __restrict__ outacc, int E) {
    int e = blockIdx.x * 4 + (threadIdx.x >> 6);
    int d = threadIdx.x & 63;
    if (e >= E) return;
    int row = ei[e];
    int col = ei[E + e];
    float norm = dis[row] * ew[e] * dis[col];
    if (d < HGCN)
        atomic_add_f32(&outacc[col * 64 + d], norm * h2[row * 64 + d]);
}

// pooled[batch[n]] += gelu(out[n] + b_gcn)
__global__ void pool_kernel(const float* __restrict__ outacc, const float* __restrict__ b_gcn,
                            const int* __restrict__ batch, float* __restrict__ pooled,
                            int n_nodes) {
    int node = blockIdx.x * 4 + (threadIdx.x >> 6);
    int d = threadIdx.x & 63;
    if (node >= n_nodes || d >= HGCN) return;
    float v = outacc[node * 64 + d] + b_gcn[d];
    atomic_add_f32(&pooled[batch[node] * 64 + d], gelu_exact(v));
}

// per-graph: fn MLP -> z = [pooled, fn_e]; z = gelu(z@W_bb1+b_bb1); logits = z@W_out+b_out
__global__ void final_kernel(const float* __restrict__ pooled,
                             const float* __restrict__ fn_avg,
                             const float* __restrict__ inf_rate,
                             const float* __restrict__ W_fn1, const float* __restrict__ b_fn1,
                             const float* __restrict__ W_fn2, const float* __restrict__ b_fn2,
                             const float* __restrict__ W_bb1, const float* __restrict__ b_bb1,
                             const float* __restrict__ W_out, const float* __restrict__ b_out,
                             float* __restrict__ logits) {
    __shared__ float z[64];
    __shared__ float t1[16];
    int g = blockIdx.x;
    int t = threadIdx.x;
    if (t < HGCN) z[t] = pooled[g * 64 + t];
    float e0 = fn_avg[g * 2], e1 = fn_avg[g * 2 + 1], e2 = inf_rate[g];
    if (t < 16) {
        float a = e0 * W_fn1[t] + e1 * W_fn1[16 + t] + e2 * W_fn1[32 + t] + b_fn1[t];
        t1[t] = gelu_exact(a);
    }
    __syncthreads();
    if (t < 3) {
        float a = b_fn2[t];
#pragma unroll
        for (int k = 0; k < 16; ++k) a += t1[k] * W_fn2[k * 3 + t];
        z[HGCN + t] = a;
    }
    __syncthreads();
    float acc = b_bb1[t];
#pragma unroll 8
    for (int k = 0; k < 64; ++k) acc += z[k] * W_bb1[k * 64 + t];
    float p = gelu_exact(acc) * W_out[t];
#pragma unroll
    for (int off = 32; off > 0; off >>= 1) p += __shfl_down(p, off);
    if (t == 0) logits[g] = p + b_out[0];
}

extern "C" void kernel_launch(void* const* d_in, const int* in_sizes, int n_in,
                              void* d_out, int out_size, void* d_ws, size_t ws_size,
                              hipStream_t stream) {
    const float* x        = (const float*)d_in[0];
    const int*   ei       = (const int*)d_in[1];
    const int*   batch    = (const int*)d_in[2];
    const int*   known    = (const int*)d_in[3];
    const int*   unk      = (const int*)d_in[4];
    const int*   obs      = (const int*)d_in[5];
    const float* fn_avg   = (const float*)d_in[6];
    const float* inf_rate = (const float*)d_in[7];
    const float* msg_w    = (const float*)d_in[8];
    const float* W_emb    = (const float*)d_in[9];
    const float* b_emb    = (const float*)d_in[10];
    const float* W_gcn    = (const float*)d_in[11];
    const float* b_gcn    = (const float*)d_in[12];
    const float* W_fn1    = (const float*)d_in[13];
    const float* b_fn1    = (const float*)d_in[14];
    const float* W_fn2    = (const float*)d_in[15];
    const float* b_fn2    = (const float*)d_in[16];
    const float* W_bb1    = (const float*)d_in[17];
    const float* b_bb1    = (const float*)d_in[18];
    const float* W_out    = (const float*)d_in[19];
    const float* b_out    = (const float*)d_in[20];
    float* logits = (float*)d_out;

    const int n_nodes = in_sizes[0] / F_IN;
    const int E       = in_sizes[1] / 2;
    const int nk = in_sizes[3], nu = in_sizes[4], no = in_sizes[5];
    const int G = in_sizes[6] / 2;

    char* ws = (char*)d_ws;
    size_t off = 0;
    auto alloc = [&](size_t bytes) -> void* {
        void* p = ws + off;
        off += (bytes + 255) & ~size_t(255);
        return p;
    };
    float* ew     = (float*)alloc(sizeof(float) * (size_t)E);
    float* h2     = (float*)alloc(sizeof(float) * (size_t)n_nodes * 64);
    float* outacc = (float*)alloc(sizeof(float) * (size_t)n_nodes * 64);
    float* deg    = (float*)alloc(sizeof(float) * (size_t)n_nodes);
    float* pooled = (float*)alloc(sizeof(float) * (size_t)G * 64);
    float* W_eff  = (float*)alloc(sizeof(float) * F_IN * 64);
    float* b_eff  = (float*)alloc(sizeof(float) * 64);
    float* sp     = (float*)alloc(sizeof(float) * 4);

    hipMemsetAsync(pooled, 0, sizeof(float) * (size_t)G * 64, stream);

    prep_kernel<<<1, 64, 0, stream>>>(msg_w, W_emb, b_emb, W_gcn, sp, W_eff, b_eff);
    init_ew_kernel<<<(E + 255) / 256, 256, 0, stream>>>(ew, E);
    set_mask_kernel<<<(nk + 255) / 256, 256, 0, stream>>>(ew, known, sp + 0, nk);
    set_mask_kernel<<<(nu + 255) / 256, 256, 0, stream>>>(ew, unk, sp + 1, nu);
    set_mask_kernel<<<(no + 255) / 256, 256, 0, stream>>>(ew, obs, sp + 2, no);
    deg_init_kernel<<<(n_nodes + 255) / 256, 256, 0, stream>>>(deg, n_nodes);
    deg_accum_kernel<<<(E + 255) / 256, 256, 0, stream>>>(ei, ew, deg, E);
    dis_kernel<<<(n_nodes + 255) / 256, 256, 0, stream>>>(deg, n_nodes);
    h2_kernel<<<(n_nodes + 3) / 4, 256, 0, stream>>>(x, W_eff, b_eff, deg, h2, outacc, n_nodes);
    scatter_kernel<<<(E + 3) / 4, 256, 0, stream>>>(ei, ew, deg, h2, outacc, E);
    pool_kernel<<<(n_nodes + 3) / 4, 256, 0, stream>>>(outacc, b_gcn, batch, pooled, n_nodes);
    final_kernel<<<G, 64, 0, stream>>>(pooled, fn_avg, inf_rate, W_fn1, b_fn1,
                                       W_fn2, b_fn2, W_bb1, b_bb1, W_out, b_out, logits);
}

// Round 2
// 659.907 us; speedup vs baseline: 1.4931x; 1.4931x over previous
//
#include <hip/hip_runtime.h>
#include <math.h>

#define F_IN 12
#define NHID 64
#define HGCN 61
#define EMB_OUT 54
#define SCAN_CH 1024

__device__ __forceinline__ float gelu_exact(float v) {
    return 0.5f * v * (1.0f + erff(v * 0.70710678118654752440f));
}

__device__ __forceinline__ void atomic_add_f32(float* p, float v) {
    unsafeAtomicAdd(p, v);   // hardware global_atomic_add_f32
}

// ---- prep: softmax(msg_weights) -> sp[3]; fold W_emb/b_emb into W_gcn -> W_eff(12x64), b_eff(64)
__global__ void prep_kernel(const float* __restrict__ msg_w,
                            const float* __restrict__ W_emb,
                            const float* __restrict__ b_emb,
                            const float* __restrict__ W_gcn,
                            float* __restrict__ sp,
                            float* __restrict__ W_eff,
                            float* __restrict__ b_eff) {
    int t = threadIdx.x;
    if (t == 0) {
        float m = fmaxf(msg_w[0], fmaxf(msg_w[1], msg_w[2]));
        float e0 = expf(msg_w[0] - m), e1 = expf(msg_w[1] - m), e2 = expf(msg_w[2] - m);
        float s = e0 + e1 + e2;
        sp[0] = e0 / s; sp[1] = e1 / s; sp[2] = e2 / s;
    }
    if (t < HGCN) {
        float be = 0.f, w0 = 0.f, w1 = 0.f;
        for (int k = 0; k < EMB_OUT; ++k) {
            float g = W_gcn[k * HGCN + t];
            be += b_emb[k] * g;
            w0 += W_emb[k] * g;
            w1 += W_emb[EMB_OUT + k] * g;
        }
        b_eff[t] = be;
        W_eff[0 * 64 + t] = w0;
        W_eff[1 * 64 + t] = w1;
        for (int f = 2; f < F_IN; ++f)
            W_eff[f * 64 + t] = W_gcn[(EMB_OUT + f - 2) * HGCN + t];
    }
}

__global__ void init_ew_kernel(float* __restrict__ ew, int E) {
    int i = blockIdx.x * blockDim.x + threadIdx.x;
    if (i < E) ew[i] = 1.0f;
}

__global__ void set_mask_kernel(float* __restrict__ ew, const int* __restrict__ mask,
                                const float* __restrict__ spv, int n) {
    int i = blockIdx.x * blockDim.x + threadIdx.x;
    if (i < n) ew[mask[i]] = *spv;
}

__global__ void deg_init_kernel(float* __restrict__ deg, int n) {
    int i = blockIdx.x * blockDim.x + threadIdx.x;
    if (i < n) deg[i] = 1.0f;   // self-loop weight
}

// pass1: per-destination edge count (int) + weighted degree (float)
__global__ void count_deg_kernel(const int* __restrict__ ei, const float* __restrict__ ew,
                                 int* __restrict__ cnt, float* __restrict__ deg, int E) {
    int e = blockIdx.x * blockDim.x + threadIdx.x;
    if (e < E) {
        int c = ei[E + e];
        atomicAdd(&cnt[c], 1);
        atomic_add_f32(&deg[c], ew[e]);
    }
}

__global__ void dis_kernel(float* __restrict__ deg, int n) {
    int i = blockIdx.x * blockDim.x + threadIdx.x;
    if (i < n) deg[i] = rsqrtf(deg[i]);   // deg >= 1 always (self-loop)
}

// ---- exclusive scan of cnt -> start (3 kernels)
__global__ void scan_partial_kernel(const int* __restrict__ cnt, int* __restrict__ startv,
                                    int* __restrict__ bsum, int n) {
    __shared__ int s[256];
    int t = threadIdx.x;
    int base = blockIdx.x * SCAN_CH + t * 4;
    int v0 = (base + 0 < n) ? cnt[base + 0] : 0;
    int v1 = (base + 1 < n) ? cnt[base + 1] : 0;
    int v2 = (base + 2 < n) ? cnt[base + 2] : 0;
    int v3 = (base + 3 < n) ? cnt[base + 3] : 0;
    int loc = v0 + v1 + v2 + v3;
    s[t] = loc;
    __syncthreads();
    for (int off = 1; off < 256; off <<= 1) {
        int u = (t >= off) ? s[t - off] : 0;
        __syncthreads();
        s[t] += u;
        __syncthreads();
    }
    int ex = s[t] - loc;
    if (t == 255) bsum[blockIdx.x] = s[255];
    if (base + 0 < n) startv[base + 0] = ex;
    if (base + 1 < n) startv[base + 1] = ex + v0;
    if (base + 2 < n) startv[base + 2] = ex + v0 + v1;
    if (base + 3 < n) startv[base + 3] = ex + v0 + v1 + v2;
}

__global__ void scan_bsum_kernel(int* __restrict__ bsum, int nb) {
    if (threadIdx.x == 0 && blockIdx.x == 0) {
        int acc = 0;
        for (int i = 0; i < nb; ++i) { int v = bsum[i]; bsum[i] = acc; acc += v; }
    }
}

__global__ void scan_add_kernel(int* __restrict__ startv, const int* __restrict__ bsum, int n) {
    int i = blockIdx.x * blockDim.x + threadIdx.x;
    if (i < n) startv[i] += bsum[i / SCAN_CH];
}

// pass2: CSR fill with (row, norm) payload
__global__ void fill_kernel(const int* __restrict__ ei, const float* __restrict__ ew,
                            const float* __restrict__ dis, const int* __restrict__ startv,
                            int* __restrict__ cursor, int2* __restrict__ payload, int E) {
    int e = blockIdx.x * blockDim.x + threadIdx.x;
    if (e >= E) return;
    int row = ei[e];
    int col = ei[E + e];
    float nrm = dis[row] * ew[e] * dis[col];
    int pos = startv[col] + atomicAdd(&cursor[col], 1);
    payload[pos] = make_int2(row, __float_as_int(nrm));
}

// h2 = x @ W_eff + b_eff (stride-64 padded, zeros at d>=61)
__global__ void h2_kernel(const float* __restrict__ x, const float* __restrict__ W_eff,
                          const float* __restrict__ b_eff,
                          float* __restrict__ h2, int n_nodes) {
    int node = blockIdx.x * 4 + (threadIdx.x >> 6);
    int d = threadIdx.x & 63;
    if (node >= n_nodes) return;
    float v = 0.f;
    if (d < HGCN) {
        v = b_eff[d];
#pragma unroll
        for (int f = 0; f < F_IN; ++f)
            v += x[node * F_IN + f] * W_eff[f * 64 + d];
    }
    h2[node * 64 + d] = v;
}

// gather (one wave per destination node) + gelu + pool, fused
__global__ void gather_pool_kernel(const int2* __restrict__ payload,
                                   const int* __restrict__ startv, const int* __restrict__ cnt,
                                   const float* __restrict__ dis, const float* __restrict__ h2,
                                   const float* __restrict__ b_gcn, const int* __restrict__ batch,
                                   float* __restrict__ pooled, int n_nodes) {
    int node = blockIdx.x * 4 + (threadIdx.x >> 6);
    int d = threadIdx.x & 63;
    if (node >= n_nodes) return;
    int s = startv[node];
    int m = cnt[node];
    float di = dis[node];
    float acc = di * di * h2[node * 64 + d];      // self-loop term
    for (int j0 = 0; j0 < m; j0 += 64) {
        int2 p = make_int2(0, 0);
        if (j0 + d < m) p = payload[s + j0 + d];  // coalesced 512B load
        int lim = min(64, m - j0);
        int k = 0;
        for (; k + 4 <= lim; k += 4) {            // 4 independent loads in flight
            int   r0 = __shfl(p.x, k),     r1 = __shfl(p.x, k + 1);
            int   r2 = __shfl(p.x, k + 2), r3 = __shfl(p.x, k + 3);
            float n0 = __int_as_float(__shfl(p.y, k));
            float n1 = __int_as_float(__shfl(p.y, k + 1));
            float n2 = __int_as_float(__shfl(p.y, k + 2));
            float n3 = __int_as_float(__shfl(p.y, k + 3));
            float h0 = h2[r0 * 64 + d], h1 = h2[r1 * 64 + d];
            float g2 = h2[r2 * 64 + d], h3 = h2[r3 * 64 + d];
            acc += n0 * h0; acc += n1 * h1; acc += n2 * g2; acc += n3 * h3;
        }
        for (; k < lim; ++k) {
            int   r = __shfl(p.x, k);
            float nv = __int_as_float(__shfl(p.y, k));
            acc += nv * h2[r * 64 + d];
        }
    }
    if (d < HGCN) {
        float v = gelu_exact(acc + b_gcn[d]);
        atomic_add_f32(&pooled[batch[node] * 64 + d], v);
    }
}

// per-graph head
__global__ void final_kernel(const float* __restrict__ pooled,
                             const float* __restrict__ fn_avg,
                             const float* __restrict__ inf_rate,
                             const float* __restrict__ W_fn1, const float* __restrict__ b_fn1,
                             const float* __restrict__ W_fn2, const float* __restrict__ b_fn2,
                             const float* __restrict__ W_bb1, const float* __restrict__ b_bb1,
                             const float* __restrict__ W_out, const float* __restrict__ b_out,
                             float* __restrict__ logits) {
    __shared__ float z[64];
    __shared__ float t1[16];
    int g = blockIdx.x;
    int t = threadIdx.x;
    if (t < HGCN) z[t] = pooled[g * 64 + t];
    float e0 = fn_avg[g * 2], e1 = fn_avg[g * 2 + 1], e2 = inf_rate[g];
    if (t < 16) {
        float a = e0 * W_fn1[t] + e1 * W_fn1[16 + t] + e2 * W_fn1[32 + t] + b_fn1[t];
        t1[t] = gelu_exact(a);
    }
    __syncthreads();
    if (t < 3) {
        float a = b_fn2[t];
#pragma unroll
        for (int k = 0; k < 16; ++k) a += t1[k] * W_fn2[k * 3 + t];
        z[HGCN + t] = a;
    }
    __syncthreads();
    float acc = b_bb1[t];
#pragma unroll 8
    for (int k = 0; k < 64; ++k) acc += z[k] * W_bb1[k * 64 + t];
    float p = gelu_exact(acc) * W_out[t];
#pragma unroll
    for (int off = 32; off > 0; off >>= 1) p += __shfl_down(p, off);
    if (t == 0) logits[g] = p + b_out[0];
}

extern "C" void kernel_launch(void* const* d_in, const int* in_sizes, int n_in,
                              void* d_out, int out_size, void* d_ws, size_t ws_size,
                              hipStream_t stream) {
    const float* x        = (const float*)d_in[0];
    const int*   ei       = (const int*)d_in[1];
    const int*   batch    = (const int*)d_in[2];
    const int*   known    = (const int*)d_in[3];
    const int*   unk      = (const int*)d_in[4];
    const int*   obs      = (const int*)d_in[5];
    const float* fn_avg   = (const float*)d_in[6];
    const float* inf_rate = (const float*)d_in[7];
    const float* msg_w    = (const float*)d_in[8];
    const float* W_emb    = (const float*)d_in[9];
    const float* b_emb    = (const float*)d_in[10];
    const float* W_gcn    = (const float*)d_in[11];
    const float* b_gcn    = (const float*)d_in[12];
    const float* W_fn1    = (const float*)d_in[13];
    const float* b_fn1    = (const float*)d_in[14];
    const float* W_fn2    = (const float*)d_in[15];
    const float* b_fn2    = (const float*)d_in[16];
    const float* W_bb1    = (const float*)d_in[17];
    const float* b_bb1    = (const float*)d_in[18];
    const float* W_out    = (const float*)d_in[19];
    const float* b_out    = (const float*)d_in[20];
    float* logits = (float*)d_out;

    const int n_nodes = in_sizes[0] / F_IN;
    const int E       = in_sizes[1] / 2;
    const int nk = in_sizes[3], nu = in_sizes[4], no = in_sizes[5];
    const int G = in_sizes[6] / 2;
    const int nb = (n_nodes + SCAN_CH - 1) / SCAN_CH;

    char* ws = (char*)d_ws;
    size_t off = 0;
    auto alloc = [&](size_t bytes) -> void* {
        void* p = ws + off;
        off += (bytes + 255) & ~size_t(255);
        return p;
    };
    float* ew      = (float*)alloc(sizeof(float) * (size_t)E);
    float* h2      = (float*)alloc(sizeof(float) * (size_t)n_nodes * 64);
    int2*  payload = (int2*)alloc(sizeof(int2) * (size_t)E);
    float* deg     = (float*)alloc(sizeof(float) * (size_t)n_nodes);
    int*   cntv    = (int*)alloc(sizeof(int) * (size_t)n_nodes);
    int*   startv  = (int*)alloc(sizeof(int) * (size_t)n_nodes);
    int*   cursor  = (int*)alloc(sizeof(int) * (size_t)n_nodes);
    int*   bsum    = (int*)alloc(sizeof(int) * (size_t)(nb + 1));
    float* pooled  = (float*)alloc(sizeof(float) * (size_t)G * 64);
    float* W_eff   = (float*)alloc(sizeof(float) * F_IN * 64);
    float* b_eff   = (float*)alloc(sizeof(float) * 64);
    float* sp      = (float*)alloc(sizeof(float) * 4);

    hipMemsetAsync(cntv,   0, sizeof(int)   * (size_t)n_nodes, stream);
    hipMemsetAsync(cursor, 0, sizeof(int)   * (size_t)n_nodes, stream);
    hipMemsetAsync(pooled, 0, sizeof(float) * (size_t)G * 64,  stream);

    prep_kernel<<<1, 64, 0, stream>>>(msg_w, W_emb, b_emb, W_gcn, sp, W_eff, b_eff);
    init_ew_kernel<<<(E + 255) / 256, 256, 0, stream>>>(ew, E);
    set_mask_kernel<<<(nk + 255) / 256, 256, 0, stream>>>(ew, known, sp + 0, nk);
    set_mask_kernel<<<(nu + 255) / 256, 256, 0, stream>>>(ew, unk, sp + 1, nu);
    set_mask_kernel<<<(no + 255) / 256, 256, 0, stream>>>(ew, obs, sp + 2, no);
    deg_init_kernel<<<(n_nodes + 255) / 256, 256, 0, stream>>>(deg, n_nodes);
    count_deg_kernel<<<(E + 255) / 256, 256, 0, stream>>>(ei, ew, cntv, deg, E);
    dis_kernel<<<(n_nodes + 255) / 256, 256, 0, stream>>>(deg, n_nodes);
    scan_partial_kernel<<<nb, 256, 0, stream>>>(cntv, startv, bsum, n_nodes);
    scan_bsum_kernel<<<1, 64, 0, stream>>>(bsum, nb);
    scan_add_kernel<<<(n_nodes + 255) / 256, 256, 0, stream>>>(startv, bsum, n_nodes);
    h2_kernel<<<(n_nodes + 3) / 4, 256, 0, stream>>>(x, W_eff, b_eff, h2, n_nodes);
    fill_kernel<<<(E + 255) / 256, 256, 0, stream>>>(ei, ew, deg, startv, cursor, payload, E);
    gather_pool_kernel<<<(n_nodes + 3) / 4, 256, 0, stream>>>(payload, startv, cntv, deg, h2,
                                                              b_gcn, batch, pooled, n_nodes);
    final_kernel<<<G, 64, 0, stream>>>(pooled, fn_avg, inf_rate, W_fn1, b_fn1,
                                       W_fn2, b_fn2, W_bb1, b_bb1, W_out, b_out, logits);
}

// Round 3
// 432.735 us; speedup vs baseline: 2.2769x; 1.5250x over previous
//
#include <hip/hip_runtime.h>
#include <math.h>

#define F_IN 12
#define NHID 64
#define HGCN 61
#define EMB_OUT 54
#define SCAN_CH 1024
#define FIX_SCALE 4194304.0f   // 2^22

__device__ __forceinline__ float gelu_exact(float v) {
    return 0.5f * v * (1.0f + erff(v * 0.70710678118654752440f));
}

__device__ __forceinline__ void atomic_add_f32(float* p, float v) {
    unsafeAtomicAdd(p, v);   // hardware global_atomic_add_f32
}

// ---- prep: softmax(msg_weights) -> sp[3]; fold W_emb/b_emb into W_gcn -> W_eff(12x64), b_eff(64)
__global__ void prep_kernel(const float* __restrict__ msg_w,
                            const float* __restrict__ W_emb,
                            const float* __restrict__ b_emb,
                            const float* __restrict__ W_gcn,
                            float* __restrict__ sp,
                            float* __restrict__ W_eff,
                            float* __restrict__ b_eff) {
    int t = threadIdx.x;
    if (t == 0) {
        float m = fmaxf(msg_w[0], fmaxf(msg_w[1], msg_w[2]));
        float e0 = expf(msg_w[0] - m), e1 = expf(msg_w[1] - m), e2 = expf(msg_w[2] - m);
        float s = e0 + e1 + e2;
        sp[0] = e0 / s; sp[1] = e1 / s; sp[2] = e2 / s;
    }
    if (t < HGCN) {
        float be = 0.f, w0 = 0.f, w1 = 0.f;
        for (int k = 0; k < EMB_OUT; ++k) {
            float g = W_gcn[k * HGCN + t];
            be += b_emb[k] * g;
            w0 += W_emb[k] * g;
            w1 += W_emb[EMB_OUT + k] * g;
        }
        b_eff[t] = be;
        W_eff[0 * 64 + t] = w0;
        W_eff[1 * 64 + t] = w1;
        for (int f = 2; f < F_IN; ++f)
            W_eff[f * 64 + t] = W_gcn[(EMB_OUT + f - 2) * HGCN + t];
    }
}

__global__ void init_ew_kernel(float* __restrict__ ew, int E) {
    int i = blockIdx.x * blockDim.x + threadIdx.x;
    if (i < E) ew[i] = 1.0f;
}

__global__ void set_mask_kernel(float* __restrict__ ew, const int* __restrict__ mask,
                                const float* __restrict__ spv, int n) {
    int i = blockIdx.x * blockDim.x + threadIdx.x;
    if (i < n) ew[mask[i]] = *spv;
}

// one u64 atomic per edge: high 22 bits = count, low 42 bits = fixed-point(2^22) weighted degree.
// Returned old value gives this edge's rank within its destination (CSR slot), no second pass.
__global__ void count_rank_kernel(const int* __restrict__ ei, const float* __restrict__ ew,
                                  unsigned long long* __restrict__ packed,
                                  int* __restrict__ rank, int E) {
    int e = blockIdx.x * blockDim.x + threadIdx.x;
    if (e >= E) return;
    int col = ei[E + e];
    unsigned long long inc = (1ULL << 42)
        | (unsigned long long)__float2uint_rn(ew[e] * FIX_SCALE);
    unsigned long long old = atomicAdd(&packed[col], inc);
    rank[e] = (int)(old >> 42);
}

// unpack: cnt (int) and dis = rsqrt(deg_edges + 1.0 self-loop)
__global__ void unpack_kernel(const unsigned long long* __restrict__ packed,
                              int* __restrict__ cnt, float* __restrict__ dis, int n) {
    int i = blockIdx.x * blockDim.x + threadIdx.x;
    if (i >= n) return;
    unsigned long long p = packed[i];
    cnt[i] = (int)(p >> 42);
    float deg = (float)(p & ((1ULL << 42) - 1)) * (1.0f / FIX_SCALE) + 1.0f;
    dis[i] = rsqrtf(deg);
}

// ---- exclusive scan of cnt -> start (3 kernels)
__global__ void scan_partial_kernel(const int* __restrict__ cnt, int* __restrict__ startv,
                                    int* __restrict__ bsum, int n) {
    __shared__ int s[256];
    int t = threadIdx.x;
    int base = blockIdx.x * SCAN_CH + t * 4;
    int v0 = (base + 0 < n) ? cnt[base + 0] : 0;
    int v1 = (base + 1 < n) ? cnt[base + 1] : 0;
    int v2 = (base + 2 < n) ? cnt[base + 2] : 0;
    int v3 = (base + 3 < n) ? cnt[base + 3] : 0;
    int loc = v0 + v1 + v2 + v3;
    s[t] = loc;
    __syncthreads();
    for (int off = 1; off < 256; off <<= 1) {
        int u = (t >= off) ? s[t - off] : 0;
        __syncthreads();
        s[t] += u;
        __syncthreads();
    }
    int ex = s[t] - loc;
    if (t == 255) bsum[blockIdx.x] = s[255];
    if (base + 0 < n) startv[base + 0] = ex;
    if (base + 1 < n) startv[base + 1] = ex + v0;
    if (base + 2 < n) startv[base + 2] = ex + v0 + v1;
    if (base + 3 < n) startv[base + 3] = ex + v0 + v1 + v2;
}

__global__ void scan_bsum_kernel(int* __restrict__ bsum, int nb) {
    if (threadIdx.x == 0 && blockIdx.x == 0) {
        int acc = 0;
        for (int i = 0; i < nb; ++i) { int v = bsum[i]; bsum[i] = acc; acc += v; }
    }
}

__global__ void scan_add_kernel(int* __restrict__ startv, const int* __restrict__ bsum, int n) {
    int i = blockIdx.x * blockDim.x + threadIdx.x;
    if (i < n) startv[i] += bsum[i / SCAN_CH];
}

// CSR fill: deterministic slot from startv + precomputed rank, NO atomic
__global__ void fill_kernel(const int* __restrict__ ei, const float* __restrict__ ew,
                            const float* __restrict__ dis, const int* __restrict__ startv,
                            const int* __restrict__ rank, int2* __restrict__ payload, int E) {
    int e = blockIdx.x * blockDim.x + threadIdx.x;
    if (e >= E) return;
    int row = ei[e];
    int col = ei[E + e];
    float nrm = dis[row] * ew[e] * dis[col];
    payload[startv[col] + rank[e]] = make_int2(row, __float_as_int(nrm));
}

// h2 = x @ W_eff + b_eff (stride-64 padded, zeros at d>=61)
__global__ void h2_kernel(const float* __restrict__ x, const float* __restrict__ W_eff,
                          const float* __restrict__ b_eff,
                          float* __restrict__ h2, int n_nodes) {
    int node = blockIdx.x * 4 + (threadIdx.x >> 6);
    int d = threadIdx.x & 63;
    if (node >= n_nodes) return;
    float v = 0.f;
    if (d < HGCN) {
        v = b_eff[d];
#pragma unroll
        for (int f = 0; f < F_IN; ++f)
            v += x[node * F_IN + f] * W_eff[f * 64 + d];
    }
    h2[node * 64 + d] = v;
}

// gather (one wave per destination node) + gelu + pool, fused
__global__ void gather_pool_kernel(const int2* __restrict__ payload,
                                   const int* __restrict__ startv, const int* __restrict__ cnt,
                                   const float* __restrict__ dis, const float* __restrict__ h2,
                                   const float* __restrict__ b_gcn, const int* __restrict__ batch,
                                   float* __restrict__ pooled, int n_nodes) {
    int node = blockIdx.x * 4 + (threadIdx.x >> 6);
    int d = threadIdx.x & 63;
    if (node >= n_nodes) return;
    int s = startv[node];
    int m = cnt[node];
    float di = dis[node];
    float acc = di * di * h2[node * 64 + d];      // self-loop term
    for (int j0 = 0; j0 < m; j0 += 64) {
        int2 p = make_int2(0, 0);
        if (j0 + d < m) p = payload[s + j0 + d];  // coalesced 512B load
        int lim = min(64, m - j0);
        int k = 0;
        for (; k + 4 <= lim; k += 4) {            // 4 independent loads in flight
            int   r0 = __shfl(p.x, k),     r1 = __shfl(p.x, k + 1);
            int   r2 = __shfl(p.x, k + 2), r3 = __shfl(p.x, k + 3);
            float n0 = __int_as_float(__shfl(p.y, k));
            float n1 = __int_as_float(__shfl(p.y, k + 1));
            float n2 = __int_as_float(__shfl(p.y, k + 2));
            float n3 = __int_as_float(__shfl(p.y, k + 3));
            float h0 = h2[r0 * 64 + d], h1 = h2[r1 * 64 + d];
            float g2 = h2[r2 * 64 + d], h3 = h2[r3 * 64 + d];
            acc += n0 * h0; acc += n1 * h1; acc += n2 * g2; acc += n3 * h3;
        }
        for (; k < lim; ++k) {
            int   r = __shfl(p.x, k);
            float nv = __int_as_float(__shfl(p.y, k));
            acc += nv * h2[r * 64 + d];
        }
    }
    if (d < HGCN) {
        float v = gelu_exact(acc + b_gcn[d]);
        atomic_add_f32(&pooled[batch[node] * 64 + d], v);
    }
}

// per-graph head
__global__ void final_kernel(const float* __restrict__ pooled,
                             const float* __restrict__ fn_avg,
                             const float* __restrict__ inf_rate,
                             const float* __restrict__ W_fn1, const float* __restrict__ b_fn1,
                             const float* __restrict__ W_fn2, const float* __restrict__ b_fn2,
                             const float* __restrict__ W_bb1, const float* __restrict__ b_bb1,
                             const float* __restrict__ W_out, const float* __restrict__ b_out,
                             float* __restrict__ logits) {
    __shared__ float z[64];
    __shared__ float t1[16];
    int g = blockIdx.x;
    int t = threadIdx.x;
    if (t < HGCN) z[t] = pooled[g * 64 + t];
    float e0 = fn_avg[g * 2], e1 = fn_avg[g * 2 + 1], e2 = inf_rate[g];
    if (t < 16) {
        float a = e0 * W_fn1[t] + e1 * W_fn1[16 + t] + e2 * W_fn1[32 + t] + b_fn1[t];
        t1[t] = gelu_exact(a);
    }
    __syncthreads();
    if (t < 3) {
        float a = b_fn2[t];
#pragma unroll
        for (int k = 0; k < 16; ++k) a += t1[k] * W_fn2[k * 3 + t];
        z[HGCN + t] = a;
    }
    __syncthreads();
    float acc = b_bb1[t];
#pragma unroll 8
    for (int k = 0; k < 64; ++k) acc += z[k] * W_bb1[k * 64 + t];
    float p = gelu_exact(acc) * W_out[t];
#pragma unroll
    for (int off = 32; off > 0; off >>= 1) p += __shfl_down(p, off);
    if (t == 0) logits[g] = p + b_out[0];
}

extern "C" void kernel_launch(void* const* d_in, const int* in_sizes, int n_in,
                              void* d_out, int out_size, void* d_ws, size_t ws_size,
                              hipStream_t stream) {
    const float* x        = (const float*)d_in[0];
    const int*   ei       = (const int*)d_in[1];
    const int*   batch    = (const int*)d_in[2];
    const int*   known    = (const int*)d_in[3];
    const int*   unk      = (const int*)d_in[4];
    const int*   obs      = (const int*)d_in[5];
    const float* fn_avg   = (const float*)d_in[6];
    const float* inf_rate = (const float*)d_in[7];
    const float* msg_w    = (const float*)d_in[8];
    const float* W_emb    = (const float*)d_in[9];
    const float* b_emb    = (const float*)d_in[10];
    const float* W_gcn    = (const float*)d_in[11];
    const float* b_gcn    = (const float*)d_in[12];
    const float* W_fn1    = (const float*)d_in[13];
    const float* b_fn1    = (const float*)d_in[14];
    const float* W_fn2    = (const float*)d_in[15];
    const float* b_fn2    = (const float*)d_in[16];
    const float* W_bb1    = (const float*)d_in[17];
    const float* b_bb1    = (const float*)d_in[18];
    const float* W_out    = (const float*)d_in[19];
    const float* b_out    = (const float*)d_in[20];
    float* logits = (float*)d_out;

    const int n_nodes = in_sizes[0] / F_IN;
    const int E       = in_sizes[1] / 2;
    const int nk = in_sizes[3], nu = in_sizes[4], no = in_sizes[5];
    const int G = in_sizes[6] / 2;
    const int nb = (n_nodes + SCAN_CH - 1) / SCAN_CH;

    char* ws = (char*)d_ws;
    size_t off = 0;
    auto alloc = [&](size_t bytes) -> void* {
        void* p = ws + off;
        off += (bytes + 255) & ~size_t(255);
        return p;
    };
    float*              ew      = (float*)alloc(sizeof(float) * (size_t)E);
    float*              h2      = (float*)alloc(sizeof(float) * (size_t)n_nodes * 64);
    int2*               payload = (int2*)alloc(sizeof(int2) * (size_t)E);
    int*                rank    = (int*)alloc(sizeof(int) * (size_t)E);
    unsigned long long* packed  = (unsigned long long*)alloc(sizeof(unsigned long long) * (size_t)n_nodes);
    float*              dis     = (float*)alloc(sizeof(float) * (size_t)n_nodes);
    int*                cntv    = (int*)alloc(sizeof(int) * (size_t)n_nodes);
    int*                startv  = (int*)alloc(sizeof(int) * (size_t)n_nodes);
    int*                bsum    = (int*)alloc(sizeof(int) * (size_t)(nb + 1));
    float*              pooled  = (float*)alloc(sizeof(float) * (size_t)G * 64);
    float*              W_eff   = (float*)alloc(sizeof(float) * F_IN * 64);
    float*              b_eff   = (float*)alloc(sizeof(float) * 64);
    float*              sp      = (float*)alloc(sizeof(float) * 4);

    hipMemsetAsync(packed, 0, sizeof(unsigned long long) * (size_t)n_nodes, stream);
    hipMemsetAsync(pooled, 0, sizeof(float) * (size_t)G * 64, stream);

    prep_kernel<<<1, 64, 0, stream>>>(msg_w, W_emb, b_emb, W_gcn, sp, W_eff, b_eff);
    init_ew_kernel<<<(E + 255) / 256, 256, 0, stream>>>(ew, E);
    set_mask_kernel<<<(nk + 255) / 256, 256, 0, stream>>>(ew, known, sp + 0, nk);
    set_mask_kernel<<<(nu + 255) / 256, 256, 0, stream>>>(ew, unk, sp + 1, nu);
    set_mask_kernel<<<(no + 255) / 256, 256, 0, stream>>>(ew, obs, sp + 2, no);
    count_rank_kernel<<<(E + 255) / 256, 256, 0, stream>>>(ei, ew, packed, rank, E);
    unpack_kernel<<<(n_nodes + 255) / 256, 256, 0, stream>>>(packed, cntv, dis, n_nodes);
    scan_partial_kernel<<<nb, 256, 0, stream>>>(cntv, startv, bsum, n_nodes);
    scan_bsum_kernel<<<1, 64, 0, stream>>>(bsum, nb);
    scan_add_kernel<<<(n_nodes + 255) / 256, 256, 0, stream>>>(startv, bsum, n_nodes);
    h2_kernel<<<(n_nodes + 3) / 4, 256, 0, stream>>>(x, W_eff, b_eff, h2, n_nodes);
    fill_kernel<<<(E + 255) / 256, 256, 0, stream>>>(ei, ew, dis, startv, rank, payload, E);
    gather_pool_kernel<<<(n_nodes + 3) / 4, 256, 0, stream>>>(payload, startv, cntv, dis, h2,
                                                              b_gcn, batch, pooled, n_nodes);
    final_kernel<<<G, 64, 0, stream>>>(pooled, fn_avg, inf_rate, W_fn1, b_fn1,
                                       W_fn2, b_fn2, W_bb1, b_bb1, W_out, b_out, logits);
}

// Round 5
// 299.117 us; speedup vs baseline: 3.2940x; 1.4467x over previous
//
#include <hip/hip_runtime.h>
#include <math.h>

#define F_IN 12
#define NHID 64
#define HGCN 61
#define EMB_OUT 54
#define SCAN_CH 1024
#define PART_R 8192           // records per partition block (LDS-staged)
#define DEG_SCALE 32768.0f    // 2^15 fixed-point for weighted degree

typedef unsigned int uint;

__device__ __forceinline__ float gelu_exact(float v) {
    return 0.5f * v * (1.0f + erff(v * 0.70710678118654752440f));
}

__device__ __forceinline__ void atomic_add_f32(float* p, float v) {
    unsafeAtomicAdd(p, v);   // hardware global_atomic_add_f32
}

// ---- prep: softmax(msg_weights) -> sp[4] (sp[3]=1), spq (fixed-point), fold W_emb into W_gcn
__global__ void prep_kernel(const float* __restrict__ msg_w,
                            const float* __restrict__ W_emb,
                            const float* __restrict__ b_emb,
                            const float* __restrict__ W_gcn,
                            float* __restrict__ sp, uint* __restrict__ spq,
                            float* __restrict__ W_eff, float* __restrict__ b_eff) {
    __shared__ float ssp[3];
    int t = threadIdx.x;
    if (t == 0) {
        float m = fmaxf(msg_w[0], fmaxf(msg_w[1], msg_w[2]));
        float e0 = expf(msg_w[0] - m), e1 = expf(msg_w[1] - m), e2 = expf(msg_w[2] - m);
        float s = e0 + e1 + e2;
        ssp[0] = e0 / s; ssp[1] = e1 / s; ssp[2] = e2 / s;
        sp[0] = ssp[0]; sp[1] = ssp[1]; sp[2] = ssp[2]; sp[3] = 1.0f;
    }
    __syncthreads();
    if (t < 4) {
        float w = (t < 3) ? ssp[t] : 1.0f;
        spq[t] = __float2uint_rn(w * DEG_SCALE);
    }
    if (t < HGCN) {
        float be = 0.f, w0 = 0.f, w1 = 0.f;
        for (int k = 0; k < EMB_OUT; ++k) {
            float g = W_gcn[k * HGCN + t];
            be += b_emb[k] * g;
            w0 += W_emb[k] * g;
            w1 += W_emb[EMB_OUT + k] * g;
        }
        b_eff[t] = be;
        W_eff[0 * 64 + t] = w0;
        W_eff[1 * 64 + t] = w1;
        for (int f = 2; f < F_IN; ++f)
            W_eff[f * 64 + t] = W_gcn[(EMB_OUT + f - 2) * HGCN + t];
    }
}

// masks write weight-class bytes (later kernel wins, like torch indexed assign)
__global__ void set_mask_u8(unsigned char* __restrict__ wclass, const int* __restrict__ mask,
                            unsigned char v, int n) {
    int i = blockIdx.x * blockDim.x + threadIdx.x;
    if (i < n) wclass[mask[i]] = v;
}

// K1: per-block histogram of destination buckets (col>>8) -> H[bucket*NBLK + blk]
__global__ __launch_bounds__(256) void k1_hist(const int* __restrict__ ei,
                                               uint* __restrict__ H,
                                               int E, int NB, int NBLK) {
    __shared__ uint hist[512];
    int blk = blockIdx.x, t = threadIdx.x;
    for (int i = t; i < 512; i += 256) hist[i] = 0;
    __syncthreads();
    int lo = blk * PART_R, hi = min(lo + PART_R, E);
    for (int i = lo + t; i < hi; i += 256)
        atomicAdd(&hist[((uint)ei[E + i]) >> 8], 1u);
    __syncthreads();
    for (int b = t; b < NB; b += 256) H[(size_t)b * NBLK + blk] = hist[b];
}

// ---- exclusive scan (3 kernels, generic length)
__global__ void scan_partial_kernel(const int* __restrict__ cnt, int* __restrict__ startv,
                                    int* __restrict__ bsum, int n) {
    __shared__ int s[256];
    int t = threadIdx.x;
    int base = blockIdx.x * SCAN_CH + t * 4;
    int v0 = (base + 0 < n) ? cnt[base + 0] : 0;
    int v1 = (base + 1 < n) ? cnt[base + 1] : 0;
    int v2 = (base + 2 < n) ? cnt[base + 2] : 0;
    int v3 = (base + 3 < n) ? cnt[base + 3] : 0;
    int loc = v0 + v1 + v2 + v3;
    s[t] = loc;
    __syncthreads();
    for (int off = 1; off < 256; off <<= 1) {
        int u = (t >= off) ? s[t - off] : 0;
        __syncthreads();
        s[t] += u;
        __syncthreads();
    }
    int ex = s[t] - loc;
    if (t == 255) bsum[blockIdx.x] = s[255];
    if (base + 0 < n) startv[base + 0] = ex;
    if (base + 1 < n) startv[base + 1] = ex + v0;
    if (base + 2 < n) startv[base + 2] = ex + v0 + v1;
    if (base + 3 < n) startv[base + 3] = ex + v0 + v1 + v2;
}

__global__ void scan_bsum_kernel(int* __restrict__ bsum, int nb) {
    if (threadIdx.x == 0 && blockIdx.x == 0) {
        int acc = 0;
        for (int i = 0; i < nb; ++i) { int v = bsum[i]; bsum[i] = acc; acc += v; }
    }
}

__global__ void scan_add_kernel(int* __restrict__ startv, const int* __restrict__ bsum, int n) {
    int i = blockIdx.x * blockDim.x + threadIdx.x;
    if (i < n) startv[i] += bsum[i / SCAN_CH];
}

// K3: LDS-staged partition to BUCKET granularity.
// Pack rec = row<<10 | (col&255)<<2 | wclass; write bucket-grouped (node-interleaved within bucket).
__global__ __launch_bounds__(256) void k3_partition(
        const int* __restrict__ ei, const unsigned char* __restrict__ wclass,
        const uint* __restrict__ Hs, uint* __restrict__ recSorted,
        int E, int NB, int NBLK) {
    __shared__ uint recs[PART_R];
    __shared__ unsigned short sbkt[PART_R];
    __shared__ uint hist[512];
    __shared__ uint scanA[512];
    __shared__ uint scanB[512];
    __shared__ int  gbase[512];
    __shared__ uint cursor[512];
    int blk = blockIdx.x, t = threadIdx.x;
    int lo = blk * PART_R, hi = min(lo + PART_R, E);
    int cntTot = hi - lo;
    hist[t] = 0; hist[t + 256] = 0;
    __syncthreads();
    for (int i = lo + t; i < hi; i += 256)
        atomicAdd(&hist[((uint)ei[E + i]) >> 8], 1u);
    __syncthreads();
    // inclusive scan of hist[0..512) (double-buffer Hillis-Steele)
    uint* src = scanA; uint* dst = scanB;
    src[t] = hist[t]; src[t + 256] = hist[t + 256];
    __syncthreads();
    for (int off = 1; off < 512; off <<= 1) {
        dst[t]       = src[t]       + ((t >= off)       ? src[t - off]       : 0u);
        dst[t + 256] = src[t + 256] + ((t + 256 >= off) ? src[t + 256 - off] : 0u);
        __syncthreads();
        uint* tmp = src; src = dst; dst = tmp;
    }
    uint l0 = (t == 0) ? 0u : src[t - 1];   // exclusive at t
    uint l1 = src[t + 255];                 // exclusive at t+256
    cursor[t] = l0; cursor[t + 256] = l1;
    if (t < NB)       gbase[t]       = (int)Hs[(size_t)t * NBLK + blk]         - (int)l0;
    if (t + 256 < NB) gbase[t + 256] = (int)Hs[(size_t)(t + 256) * NBLK + blk] - (int)l1;
    __syncthreads();
    for (int i = lo + t; i < hi; i += 256) {
        uint row = (uint)ei[i];
        uint col = (uint)ei[E + i];
        uint b = col >> 8;
        uint rec = (row << 10) | ((col & 255u) << 2) | (uint)wclass[i];
        uint slot = atomicAdd(&cursor[b], 1u);
        recs[slot] = rec;
        sbkt[slot] = (unsigned short)b;
    }
    __syncthreads();
    for (int s = t; s < cntTot; s += 256)
        recSorted[gbase[sbkt[s]] + s] = recs[s];
}

// K2: per-bucket node stats: cnt, startv (node-exact global CSR offset), dis = rsqrt(deg+1)
__global__ __launch_bounds__(256) void k2_stats(
        const uint* __restrict__ recSorted, const uint* __restrict__ Hs,
        const uint* __restrict__ spq,
        uint* __restrict__ cnt, uint* __restrict__ startv, float* __restrict__ dis,
        int E, int NB, int NBLK, int n_nodes) {
    __shared__ uint hcnt[256], hdeg[256], sA[256], sB[256];
    __shared__ uint sq[4];
    int b = blockIdx.x, t = threadIdx.x;
    hcnt[t] = 0; hdeg[t] = 0;
    if (t < 4) sq[t] = spq[t];
    __syncthreads();
    uint lo = Hs[(size_t)b * NBLK];
    uint hi = (b + 1 < NB) ? Hs[(size_t)(b + 1) * NBLK] : (uint)E;
    for (uint i = lo + t; i < hi; i += 256) {
        uint r = recSorted[i];
        atomicAdd(&hcnt[(r >> 2) & 255u], 1u);
        atomicAdd(&hdeg[(r >> 2) & 255u], sq[r & 3u]);
    }
    __syncthreads();
    uint* src = sA; uint* dst = sB;
    src[t] = hcnt[t];
    __syncthreads();
    for (int off = 1; off < 256; off <<= 1) {
        dst[t] = src[t] + ((t >= off) ? src[t - off] : 0u);
        __syncthreads();
        uint* tmp = src; src = dst; dst = tmp;
    }
    uint excl = (t == 0) ? 0u : src[t - 1];
    int node = (b << 8) + t;
    if (node < n_nodes) {
        cnt[node] = hcnt[t];
        startv[node] = lo + excl;
        float deg = (float)hdeg[t] * (1.0f / DEG_SCALE) + 1.0f;
        dis[node] = rsqrtf(deg);
    }
}

// K4: second-level partition + payload fill. One block per bucket: LDS cursors start at
// node-exact CSR offsets; each record lands at its final node-grouped position.
// Scattered writes stay inside this bucket's ~64KB payload window -> L2 write-back absorbs.
__global__ __launch_bounds__(256) void k4_payload(
        const uint* __restrict__ recSorted, const uint* __restrict__ Hs,
        const float* __restrict__ sp, const float* __restrict__ dis,
        const uint* __restrict__ startv,
        int2* __restrict__ payload, int E, int NB, int NBLK, int n_nodes) {
    __shared__ float disl[256];
    __shared__ uint cur[256];
    __shared__ float spl[4];
    int b = blockIdx.x, t = threadIdx.x;
    int node = (b << 8) + t;
    disl[t] = (node < n_nodes) ? dis[node] : 0.0f;
    cur[t]  = (node < n_nodes) ? startv[node] : 0u;
    if (t < 4) spl[t] = sp[t];
    __syncthreads();
    uint lo = Hs[(size_t)b * NBLK];
    uint hi = (b + 1 < NB) ? Hs[(size_t)(b + 1) * NBLK] : (uint)E;
    for (uint i = lo + t; i < hi; i += 256) {
        uint r = recSorted[i];
        uint row = r >> 10;
        uint c = (r >> 2) & 255u;
        float nrm = dis[row] * spl[r & 3u] * disl[c];
        uint pos = atomicAdd(&cur[c], 1u);
        payload[pos] = make_int2((int)row, __float_as_int(nrm));
    }
}

// h2 = x @ W_eff + b_eff (stride-64 padded, zeros at d>=61)
__global__ void h2_kernel(const float* __restrict__ x, const float* __restrict__ W_eff,
                          const float* __restrict__ b_eff,
                          float* __restrict__ h2, int n_nodes) {
    int node = blockIdx.x * 4 + (threadIdx.x >> 6);
    int d = threadIdx.x & 63;
    if (node >= n_nodes) return;
    float v = 0.f;
    if (d < HGCN) {
        v = b_eff[d];
#pragma unroll
        for (int f = 0; f < F_IN; ++f)
            v += x[node * F_IN + f] * W_eff[f * 64 + d];
    }
    h2[node * 64 + d] = v;
}

// gather (one wave per destination node) + gelu + pool, fused
__global__ void gather_pool_kernel(const int2* __restrict__ payload,
                                   const uint* __restrict__ startv, const uint* __restrict__ cnt,
                                   const float* __restrict__ dis, const float* __restrict__ h2,
                                   const float* __restrict__ b_gcn, const int* __restrict__ batch,
                                   float* __restrict__ pooled, int n_nodes) {
    int node = blockIdx.x * 4 + (threadIdx.x >> 6);
    int d = threadIdx.x & 63;
    if (node >= n_nodes) return;
    int s = (int)startv[node];
    int m = (int)cnt[node];
    float di = dis[node];
    float acc = di * di * h2[node * 64 + d];      // self-loop term
    for (int j0 = 0; j0 < m; j0 += 64) {
        int2 p = make_int2(0, 0);
        if (j0 + d < m) p = payload[s + j0 + d];  // coalesced 512B load
        int lim = min(64, m - j0);
        int k = 0;
        for (; k + 4 <= lim; k += 4) {            // 4 independent loads in flight
            int   r0 = __shfl(p.x, k),     r1 = __shfl(p.x, k + 1);
            int   r2 = __shfl(p.x, k + 2), r3 = __shfl(p.x, k + 3);
            float n0 = __int_as_float(__shfl(p.y, k));
            float n1 = __int_as_float(__shfl(p.y, k + 1));
            float n2 = __int_as_float(__shfl(p.y, k + 2));
            float n3 = __int_as_float(__shfl(p.y, k + 3));
            float h0 = h2[r0 * 64 + d], h1 = h2[r1 * 64 + d];
            float g2 = h2[r2 * 64 + d], h3 = h2[r3 * 64 + d];
            acc += n0 * h0; acc += n1 * h1; acc += n2 * g2; acc += n3 * h3;
        }
        for (; k < lim; ++k) {
            int   r = __shfl(p.x, k);
            float nv = __int_as_float(__shfl(p.y, k));
            acc += nv * h2[r * 64 + d];
        }
    }
    if (d < HGCN) {
        float v = gelu_exact(acc + b_gcn[d]);
        atomic_add_f32(&pooled[batch[node] * 64 + d], v);
    }
}

// per-graph head
__global__ void final_kernel(const float* __restrict__ pooled,
                             const float* __restrict__ fn_avg,
                             const float* __restrict__ inf_rate,
                             const float* __restrict__ W_fn1, const float* __restrict__ b_fn1,
                             const float* __restrict__ W_fn2, const float* __restrict__ b_fn2,
                             const float* __restrict__ W_bb1, const float* __restrict__ b_bb1,
                             const float* __restrict__ W_out, const float* __restrict__ b_out,
                             float* __restrict__ logits) {
    __shared__ float z[64];
    __shared__ float t1[16];
    int g = blockIdx.x;
    int t = threadIdx.x;
    if (t < HGCN) z[t] = pooled[g * 64 + t];
    float e0 = fn_avg[g * 2], e1 = fn_avg[g * 2 + 1], e2 = inf_rate[g];
    if (t < 16) {
        float a = e0 * W_fn1[t] + e1 * W_fn1[16 + t] + e2 * W_fn1[32 + t] + b_fn1[t];
        t1[t] = gelu_exact(a);
    }
    __syncthreads();
    if (t < 3) {
        float a = b_fn2[t];
#pragma unroll
        for (int k = 0; k < 16; ++k) a += t1[k] * W_fn2[k * 3 + t];
        z[HGCN + t] = a;
    }
    __syncthreads();
    float acc = b_bb1[t];
#pragma unroll 8
    for (int k = 0; k < 64; ++k) acc += z[k] * W_bb1[k * 64 + t];
    float p = gelu_exact(acc) * W_out[t];
#pragma unroll
    for (int off = 32; off > 0; off >>= 1) p += __shfl_down(p, off);
    if (t == 0) logits[g] = p + b_out[0];
}

extern "C" void kernel_launch(void* const* d_in, const int* in_sizes, int n_in,
                              void* d_out, int out_size, void* d_ws, size_t ws_size,
                              hipStream_t stream) {
    const float* x        = (const float*)d_in[0];
    const int*   ei       = (const int*)d_in[1];
    const int*   batch    = (const int*)d_in[2];
    const int*   known    = (const int*)d_in[3];
    const int*   unk      = (const int*)d_in[4];
    const int*   obs      = (const int*)d_in[5];
    const float* fn_avg   = (const float*)d_in[6];
    const float* inf_rate = (const float*)d_in[7];
    const float* msg_w    = (const float*)d_in[8];
    const float* W_emb    = (const float*)d_in[9];
    const float* b_emb    = (const float*)d_in[10];
    const float* W_gcn    = (const float*)d_in[11];
    const float* b_gcn    = (const float*)d_in[12];
    const float* W_fn1    = (const float*)d_in[13];
    const float* b_fn1    = (const float*)d_in[14];
    const float* W_fn2    = (const float*)d_in[15];
    const float* b_fn2    = (const float*)d_in[16];
    const float* W_bb1    = (const float*)d_in[17];
    const float* b_bb1    = (const float*)d_in[18];
    const float* W_out    = (const float*)d_in[19];
    const float* b_out    = (const float*)d_in[20];
    float* logits = (float*)d_out;

    const int n_nodes = in_sizes[0] / F_IN;
    const int E       = in_sizes[1] / 2;
    const int nk = in_sizes[3], nu = in_sizes[4], no = in_sizes[5];
    const int G = in_sizes[6] / 2;

    const int NB   = (n_nodes + 255) >> 8;
    const int NBLK = (E + PART_R - 1) / PART_R;
    const int L    = NB * NBLK;
    const int nbL  = (L + SCAN_CH - 1) / SCAN_CH;

    char* ws = (char*)d_ws;
    size_t off = 0;
    auto alloc = [&](size_t bytes) -> void* {
        void* p = ws + off;
        off += (bytes + 255) & ~size_t(255);
        return p;
    };
    unsigned char* wclass    = (unsigned char*)alloc(sizeof(unsigned char) * (size_t)E);
    uint*          recSorted = (uint*)alloc(sizeof(uint) * (size_t)E);
    uint*          H         = (uint*)alloc(sizeof(uint) * (size_t)L);
    uint*          Hs        = (uint*)alloc(sizeof(uint) * (size_t)L);
    int*           bsum      = (int*)alloc(sizeof(int) * (size_t)(nbL + 1));
    float*         h2        = (float*)alloc(sizeof(float) * (size_t)n_nodes * 64);
    int2*          payload   = (int2*)alloc(sizeof(int2) * (size_t)E);
    uint*          cntv      = (uint*)alloc(sizeof(uint) * (size_t)n_nodes);
    uint*          startv    = (uint*)alloc(sizeof(uint) * (size_t)n_nodes);
    float*         dis       = (float*)alloc(sizeof(float) * (size_t)n_nodes);
    float*         pooled    = (float*)alloc(sizeof(float) * (size_t)G * 64);
    float*         W_eff     = (float*)alloc(sizeof(float) * F_IN * 64);
    float*         b_eff     = (float*)alloc(sizeof(float) * 64);
    float*         sp        = (float*)alloc(sizeof(float) * 4);
    uint*          spq       = (uint*)alloc(sizeof(uint) * 4);

    hipMemsetAsync(wclass, 3, sizeof(unsigned char) * (size_t)E, stream);  // class 3 = weight 1.0
    hipMemsetAsync(pooled, 0, sizeof(float) * (size_t)G * 64, stream);

    prep_kernel<<<1, 64, 0, stream>>>(msg_w, W_emb, b_emb, W_gcn, sp, spq, W_eff, b_eff);
    set_mask_u8<<<(nk + 255) / 256, 256, 0, stream>>>(wclass, known, 0, nk);
    set_mask_u8<<<(nu + 255) / 256, 256, 0, stream>>>(wclass, unk, 1, nu);
    set_mask_u8<<<(no + 255) / 256, 256, 0, stream>>>(wclass, obs, 2, no);
    k1_hist<<<NBLK, 256, 0, stream>>>(ei, H, E, NB, NBLK);
    scan_partial_kernel<<<nbL, 256, 0, stream>>>((const int*)H, (int*)Hs, bsum, L);
    scan_bsum_kernel<<<1, 64, 0, stream>>>(bsum, nbL);
    scan_add_kernel<<<(L + 255) / 256, 256, 0, stream>>>((int*)Hs, bsum, L);
    k3_partition<<<NBLK, 256, 0, stream>>>(ei, wclass, Hs, recSorted, E, NB, NBLK);
    k2_stats<<<NB, 256, 0, stream>>>(recSorted, Hs, spq, cntv, startv, dis, E, NB, NBLK, n_nodes);
    h2_kernel<<<(n_nodes + 3) / 4, 256, 0, stream>>>(x, W_eff, b_eff, h2, n_nodes);
    k4_payload<<<NB, 256, 0, stream>>>(recSorted, Hs, sp, dis, startv, payload, E, NB, NBLK, n_nodes);
    gather_pool_kernel<<<(n_nodes + 3) / 4, 256, 0, stream>>>(payload, startv, cntv, dis, h2,
                                                              b_gcn, batch, pooled, n_nodes);
    final_kernel<<<G, 64, 0, stream>>>(pooled, fn_avg, inf_rate, W_fn1, b_fn1,
                                       W_fn2, b_fn2, W_bb1, b_bb1, W_out, b_out, logits);
}